// Round 5
// baseline (406.691 us; speedup 1.0000x reference)
//
#include <hip/hip_runtime.h>
#include <cstdint>
#include <cstddef>

typedef __attribute__((ext_vector_type(8))) short short8v;   // 8 bf16 / 4 VGPRs
typedef __attribute__((ext_vector_type(4))) float f32x4;

#define BSHIFT 9            // 512 nodes per bucket
#define NBUCK_MAX 256

__device__ __forceinline__ unsigned short f2bf_rne(float x) {
    unsigned int u = __float_as_uint(x);
    return (unsigned short)((u + 0x7fffu + ((u >> 16) & 1u)) >> 16);
}
__device__ __forceinline__ float bf2f(unsigned short h) {
    return __uint_as_float(((unsigned int)h) << 16);
}
__device__ __forceinline__ float bflo(unsigned int u) { return __uint_as_float(u << 16); }
__device__ __forceinline__ float bfhi(unsigned int u) { return __uint_as_float(u & 0xffff0000u); }

__device__ __forceinline__ void acc8(float* a, uint4 v) {
    a[0] += bflo(v.x); a[1] += bfhi(v.x);
    a[2] += bflo(v.y); a[3] += bfhi(v.y);
    a[4] += bflo(v.z); a[5] += bfhi(v.z);
    a[6] += bflo(v.w); a[7] += bfhi(v.w);
}

// ---------------- CSR build: bucketed (512 nodes/bucket) ----------------

__global__ __launch_bounds__(256) void k_hist(const int* __restrict__ dstv,
                                              int* __restrict__ gcnt, int E) {
    __shared__ int h[NBUCK_MAX];
    int t = threadIdx.x;
    for (int b = t; b < NBUCK_MAX; b += 256) h[b] = 0;
    __syncthreads();
    int base = blockIdx.x * 4096;
    for (int q = 0; q < 16; ++q) {
        int i = base + q * 256 + t;
        if (i < E) atomicAdd(&h[dstv[i] >> BSHIFT], 1);
    }
    __syncthreads();
    for (int b = t; b < NBUCK_MAX; b += 256)
        if (h[b]) atomicAdd(&gcnt[b], h[b]);
}

__global__ __launch_bounds__(256) void k_scanb(const int* __restrict__ gcnt,
                                               int* __restrict__ bstart,
                                               int* __restrict__ bcur, int nbuck, int E) {
    __shared__ int s[256];
    int t = threadIdx.x;
    int v = (t < nbuck) ? gcnt[t] : 0;
    s[t] = v;
    __syncthreads();
    for (int off = 1; off < 256; off <<= 1) {
        int x = 0;
        if (t >= off) x = s[t - off];
        __syncthreads();
        if (t >= off) s[t] += x;
        __syncthreads();
    }
    if (t < nbuck) { int ex = s[t] - v; bstart[t] = ex; bcur[t] = ex; }
    if (t == 0) bstart[nbuck] = E;
}

__global__ __launch_bounds__(256) void k_scatb(const int* __restrict__ srcv,
                                               const int* __restrict__ dstv,
                                               int* __restrict__ bcur,
                                               unsigned long long* __restrict__ ebuf, int E) {
    __shared__ int hcnt[NBUCK_MAX], hbase[NBUCK_MAX], hcur[NBUCK_MAX];
    int t = threadIdx.x;
    for (int b = t; b < NBUCK_MAX; b += 256) { hcnt[b] = 0; hcur[b] = 0; }
    __syncthreads();
    int base = blockIdx.x * 4096;
    for (int q = 0; q < 16; ++q) {
        int i = base + q * 256 + t;
        if (i < E) atomicAdd(&hcnt[dstv[i] >> BSHIFT], 1);
    }
    __syncthreads();
    for (int b = t; b < NBUCK_MAX; b += 256)
        hbase[b] = hcnt[b] ? atomicAdd(&bcur[b], hcnt[b]) : 0;
    __syncthreads();
    for (int q = 0; q < 16; ++q) {
        int i = base + q * 256 + t;
        if (i < E) {
            int d = dstv[i], b = d >> BSHIFT;
            int off = atomicAdd(&hcur[b], 1);
            ebuf[hbase[b] + off] =
                (unsigned long long)(unsigned)srcv[i] | ((unsigned long long)(unsigned)d << 32);
        }
    }
}

__global__ __launch_bounds__(512) void k_bsort(const unsigned long long* __restrict__ ebuf,
                                               const int* __restrict__ bstart,
                                               int* __restrict__ colv,
                                               int* __restrict__ rowstart,
                                               float* __restrict__ dinv,
                                               int n, int nbuck, int E) {
    __shared__ int cnt[512], sc[512], cur[512];
    int t = threadIdx.x;
    int b = blockIdx.x;
    int node0 = b << BSHIFT;
    int nn = min(512, n - node0);
    cnt[t] = 0;
    __syncthreads();
    int s0 = bstart[b], e0 = bstart[b + 1];
    for (int i = s0 + t; i < e0; i += 512) {
        int d = (int)(ebuf[i] >> 32);
        atomicAdd(&cnt[d - node0], 1);
    }
    __syncthreads();
    int v = cnt[t];
    sc[t] = v;
    __syncthreads();
    for (int off = 1; off < 512; off <<= 1) {
        int x = 0;
        if (t >= off) x = sc[t - off];
        __syncthreads();
        if (t >= off) sc[t] += x;
        __syncthreads();
    }
    if (t < nn) {
        int rs = s0 + sc[t] - v;
        cur[t] = rs;
        rowstart[node0 + t] = rs;
        dinv[node0 + t] = rsqrtf((float)(v + 1));   // +1 self-loop
    }
    if (b == nbuck - 1 && t == 0) rowstart[n] = E;
    __syncthreads();
    for (int i = s0 + t; i < e0; i += 512) {
        unsigned long long pv = ebuf[i];
        int d = (int)(pv >> 32);
        int pos = atomicAdd(&cur[d - node0], 1);
        colv[pos] = (int)(unsigned)(pv & 0xffffffffu);
    }
}

// ---------------- weight prep: split f32 -> bf16 hi/lo, transposed [mfma_col][K] ----------------
// MFMA col c -> output channel ch(c) = (c&15)*8 + (c>>4): lane lr owns channels lr*8..lr*8+7.

__global__ __launch_bounds__(256) void k_prepB(const float* __restrict__ W1,
                                               const float* __restrict__ Wmu,
                                               const float* __restrict__ Wls,
                                               unsigned short* __restrict__ B1h,
                                               unsigned short* __restrict__ B1l,
                                               unsigned short* __restrict__ B2h,
                                               unsigned short* __restrict__ B2l) {
    int i = blockIdx.x * 256 + threadIdx.x;
    if (i < 256 * 128) {               // W1 [256][128]
        int k = i >> 7, c = i & 127;
        int ch = ((c & 15) << 3) | (c >> 4);
        float vv = W1[k * 128 + ch];
        unsigned short h = f2bf_rne(vv);
        B1h[c * 256 + k] = h;
        B1l[c * 256 + k] = f2bf_rne(vv - bf2f(h));
    }
    if (i < 128 * 128) {               // [Wmu|Wls] [128][128]
        int k = i >> 7, c = i & 127;
        int ch = ((c & 15) << 3) | (c >> 4);
        float vv = (ch < 64) ? Wmu[k * 64 + ch] : Wls[k * 64 + (ch - 64)];
        unsigned short h = f2bf_rne(vv);
        B2h[c * 128 + k] = h;
        B2l[c * 128 + k] = f2bf_rne(vv - bf2f(h));
    }
}

// ---------------- GEMM1: h' = dinv .* (x @ W1), out bf16 [n][128] ----------------
// 16 rows x 128 cols per wave (32 AGPR acc), next-k prefetch, no LDS/barriers.

__global__ __launch_bounds__(256) void k_gemm1(const float* __restrict__ A,
                                               const unsigned short* __restrict__ Bth,
                                               const unsigned short* __restrict__ Btl,
                                               const float* __restrict__ dinv,
                                               unsigned short* __restrict__ Cb, int M) {
    const int K = 256;
    const int tid = threadIdx.x;
    const int wv = tid >> 6, l = tid & 63;
    const int lr = l & 15, lk = (l >> 4) * 8;
    const int row0 = blockIdx.x * 64 + wv * 16;

    f32x4 acc[8];
#pragma unroll
    for (int ct = 0; ct < 8; ++ct) acc[ct] = (f32x4){0.f, 0.f, 0.f, 0.f};

    int rg = row0 + lr;
    const float* ap = A + (size_t)(rg < M ? rg : 0) * K + lk;

    float4 fa = *(const float4*)(ap);
    float4 fb = *(const float4*)(ap + 4);

    for (int k0 = 0; k0 < K; k0 += 32) {
        float4 na, nb;
        if (k0 + 32 < K) {
            na = *(const float4*)(ap + k0 + 32);
            nb = *(const float4*)(ap + k0 + 36);
        }
        float av[8] = {fa.x, fa.y, fa.z, fa.w, fb.x, fb.y, fb.z, fb.w};
        short8v ah, al;
#pragma unroll
        for (int q = 0; q < 8; ++q) {
            unsigned short h = f2bf_rne(av[q]);
            ah[q] = (short)h;
            al[q] = (short)f2bf_rne(av[q] - bf2f(h));
        }
#pragma unroll
        for (int ct = 0; ct < 8; ++ct) {
            const size_t bo = (size_t)(ct * 16 + lr) * K + k0 + lk;
            short8v bh = *(const short8v*)(Bth + bo);
            short8v bl = *(const short8v*)(Btl + bo);
            acc[ct] = __builtin_amdgcn_mfma_f32_16x16x32_bf16(ah, bh, acc[ct], 0, 0, 0);
            acc[ct] = __builtin_amdgcn_mfma_f32_16x16x32_bf16(al, bh, acc[ct], 0, 0, 0);
            acc[ct] = __builtin_amdgcn_mfma_f32_16x16x32_bf16(ah, bl, acc[ct], 0, 0, 0);
        }
        fa = na; fb = nb;
    }

    // D: col(lane&15) = MFMA col ct*16+lr -> channel lr*8+ct ; row = (l>>4)*4 + j
    int rbase = row0 + ((l >> 4) << 2);
#pragma unroll
    for (int j = 0; j < 4; ++j) {
        int row = rbase + j;
        if (row < M) {
            float dv = dinv[row];
            short8v r;
#pragma unroll
            for (int ct = 0; ct < 8; ++ct) r[ct] = (short)f2bf_rne(dv * acc[ct][j]);
            *(short8v*)(Cb + (size_t)row * 128 + lr * 8) = r;
        }
    }
}

// ---------------- prop1: hidden' = dinv .* relu(dinv_v * (sum h'_c + h'_v) + b1), bf16 ----------------

__global__ __launch_bounds__(256) void k_prop1(const unsigned short* __restrict__ hb,
                                               const int* __restrict__ colv,
                                               const int* __restrict__ rowstart,
                                               const float* __restrict__ dinv,
                                               const float* __restrict__ bias,
                                               unsigned short* __restrict__ ob, int n) {
    int wid = (blockIdx.x * 256 + threadIdx.x) >> 6;
    if (wid >= n) return;
    int lane = threadIdx.x & 63;
    int q = lane >> 4, cl = lane & 15;
    int s = rowstart[wid], cnt = rowstart[wid + 1] - s;
    float a[8] = {0.f, 0.f, 0.f, 0.f, 0.f, 0.f, 0.f, 0.f};
    int i = 0;
    for (; i + 16 <= cnt; i += 16) {
        int c0 = colv[s + i + q];
        int c1 = colv[s + i + 4 + q];
        int c2 = colv[s + i + 8 + q];
        int c3 = colv[s + i + 12 + q];
        uint4 v0 = *(const uint4*)(hb + (size_t)c0 * 128 + cl * 8);
        uint4 v1 = *(const uint4*)(hb + (size_t)c1 * 128 + cl * 8);
        uint4 v2 = *(const uint4*)(hb + (size_t)c2 * 128 + cl * 8);
        uint4 v3 = *(const uint4*)(hb + (size_t)c3 * 128 + cl * 8);
        acc8(a, v0); acc8(a, v1); acc8(a, v2); acc8(a, v3);
    }
    for (; i + 4 <= cnt; i += 4) {
        int c = colv[s + i + q];
        uint4 v = *(const uint4*)(hb + (size_t)c * 128 + cl * 8);
        acc8(a, v);
    }
    if (q < cnt - i) {
        int c = colv[s + i + q];
        uint4 v = *(const uint4*)(hb + (size_t)c * 128 + cl * 8);
        acc8(a, v);
    }
#pragma unroll
    for (int k = 0; k < 8; ++k) {
        a[k] += __shfl_xor(a[k], 16);
        a[k] += __shfl_xor(a[k], 32);
    }
    if (q == 0) {
        uint4 vo = *(const uint4*)(hb + (size_t)wid * 128 + cl * 8);  // self-loop
        acc8(a, vo);
        float dv = dinv[wid];
        float4 b0 = *(const float4*)(bias + cl * 8);
        float4 b1v = *(const float4*)(bias + cl * 8 + 4);
        float bb[8] = {b0.x, b0.y, b0.z, b0.w, b1v.x, b1v.y, b1v.z, b1v.w};
        short8v r;
#pragma unroll
        for (int k = 0; k < 8; ++k) {
            float o = fmaxf(a[k] * dv + bb[k], 0.f) * dv;   // fold next-layer dinv
            r[k] = (short)f2bf_rne(o);
        }
        *(short8v*)(ob + (size_t)wid * 128 + cl * 8) = r;
    }
}

// ---------------- prop2: agg = dinv_v * (sum hidden'_c + hidden'_v), bf16 ----------------

__global__ __launch_bounds__(256) void k_prop2(const unsigned short* __restrict__ hb,
                                               const int* __restrict__ colv,
                                               const int* __restrict__ rowstart,
                                               const float* __restrict__ dinv,
                                               unsigned short* __restrict__ ob, int n) {
    int wid = (blockIdx.x * 256 + threadIdx.x) >> 6;
    if (wid >= n) return;
    int lane = threadIdx.x & 63;
    int q = lane >> 4, cl = lane & 15;
    int s = rowstart[wid], cnt = rowstart[wid + 1] - s;
    float a[8] = {0.f, 0.f, 0.f, 0.f, 0.f, 0.f, 0.f, 0.f};
    int i = 0;
    for (; i + 16 <= cnt; i += 16) {
        int c0 = colv[s + i + q];
        int c1 = colv[s + i + 4 + q];
        int c2 = colv[s + i + 8 + q];
        int c3 = colv[s + i + 12 + q];
        uint4 v0 = *(const uint4*)(hb + (size_t)c0 * 128 + cl * 8);
        uint4 v1 = *(const uint4*)(hb + (size_t)c1 * 128 + cl * 8);
        uint4 v2 = *(const uint4*)(hb + (size_t)c2 * 128 + cl * 8);
        uint4 v3 = *(const uint4*)(hb + (size_t)c3 * 128 + cl * 8);
        acc8(a, v0); acc8(a, v1); acc8(a, v2); acc8(a, v3);
    }
    for (; i + 4 <= cnt; i += 4) {
        int c = colv[s + i + q];
        uint4 v = *(const uint4*)(hb + (size_t)c * 128 + cl * 8);
        acc8(a, v);
    }
    if (q < cnt - i) {
        int c = colv[s + i + q];
        uint4 v = *(const uint4*)(hb + (size_t)c * 128 + cl * 8);
        acc8(a, v);
    }
#pragma unroll
    for (int k = 0; k < 8; ++k) {
        a[k] += __shfl_xor(a[k], 16);
        a[k] += __shfl_xor(a[k], 32);
    }
    if (q == 0) {
        uint4 vo = *(const uint4*)(hb + (size_t)wid * 128 + cl * 8);
        acc8(a, vo);
        float dv = dinv[wid];
        short8v r;
#pragma unroll
        for (int k = 0; k < 8; ++k) r[k] = (short)f2bf_rne(a[k] * dv);
        *(short8v*)(ob + (size_t)wid * 128 + cl * 8) = r;
    }
}

// ---------------- GEMM2 + epilogue: [mu|ls] = agg @ [Wmu|Wls] + b ; z = mu + eps*exp(ls) ----------------
// 16 rows x 128 cols per wave; A bf16 exact, B split hi/lo (2 MFMA per ct).

__global__ __launch_bounds__(256) void k_gemm2z(const unsigned short* __restrict__ Ab,
                                                const unsigned short* __restrict__ Bth,
                                                const unsigned short* __restrict__ Btl,
                                                const float* __restrict__ bmu,
                                                const float* __restrict__ bls,
                                                const float* __restrict__ eps,
                                                float* __restrict__ zout,
                                                float* __restrict__ muout,
                                                float* __restrict__ lsout, int M) {
    const int K = 128;
    const int tid = threadIdx.x;
    const int wv = tid >> 6, l = tid & 63;
    const int lr = l & 15, lk = (l >> 4) * 8;
    const int row0 = blockIdx.x * 64 + wv * 16;

    f32x4 acc[8];
#pragma unroll
    for (int ct = 0; ct < 8; ++ct) acc[ct] = (f32x4){0.f, 0.f, 0.f, 0.f};

    int rg = row0 + lr;
    const unsigned short* ap = Ab + (size_t)(rg < M ? rg : 0) * K + lk;

    short8v a0 = *(const short8v*)(ap);
    for (int k0 = 0; k0 < K; k0 += 32) {
        short8v an;
        if (k0 + 32 < K) an = *(const short8v*)(ap + k0 + 32);
#pragma unroll
        for (int ct = 0; ct < 8; ++ct) {
            const size_t bo = (size_t)(ct * 16 + lr) * K + k0 + lk;
            short8v bh = *(const short8v*)(Bth + bo);
            short8v bl = *(const short8v*)(Btl + bo);
            acc[ct] = __builtin_amdgcn_mfma_f32_16x16x32_bf16(a0, bh, acc[ct], 0, 0, 0);
            acc[ct] = __builtin_amdgcn_mfma_f32_16x16x32_bf16(a0, bl, acc[ct], 0, 0, 0);
        }
        a0 = an;
    }

    const bool isMu = (lr < 8);
    float bb[8];
#pragma unroll
    for (int ct = 0; ct < 8; ++ct)
        bb[ct] = isMu ? bmu[lr * 8 + ct] : bls[(lr - 8) * 8 + ct];

    int rbase = row0 + ((l >> 4) << 2);
#pragma unroll
    for (int j = 0; j < 4; ++j) {
        int row = rbase + j;
        float val[8], ex[8], exs[8];
#pragma unroll
        for (int ct = 0; ct < 8; ++ct) {
            val[ct] = acc[ct][j] + bb[ct];
            ex[ct] = __expf(val[ct]);
        }
#pragma unroll
        for (int ct = 0; ct < 8; ++ct) exs[ct] = __shfl(ex[ct], l + 8);  // ls partner
        if (row < M) {
            if (isMu) {
                size_t o = (size_t)row * 64 + lr * 8;
                float4 e0 = *(const float4*)(eps + o);
                float4 e1 = *(const float4*)(eps + o + 4);
                float epv[8] = {e0.x, e0.y, e0.z, e0.w, e1.x, e1.y, e1.z, e1.w};
                float z[8];
#pragma unroll
                for (int ct = 0; ct < 8; ++ct) z[ct] = val[ct] + epv[ct] * exs[ct];
                *(float4*)(zout + o)     = make_float4(z[0], z[1], z[2], z[3]);
                *(float4*)(zout + o + 4) = make_float4(z[4], z[5], z[6], z[7]);
                *(float4*)(muout + o)     = make_float4(val[0], val[1], val[2], val[3]);
                *(float4*)(muout + o + 4) = make_float4(val[4], val[5], val[6], val[7]);
            } else {
                size_t o = (size_t)row * 64 + (lr - 8) * 8;
                *(float4*)(lsout + o)     = make_float4(val[0], val[1], val[2], val[3]);
                *(float4*)(lsout + o + 4) = make_float4(val[4], val[5], val[6], val[7]);
            }
        }
    }
}

// ---------------- launch ----------------

extern "C" void kernel_launch(void* const* d_in, const int* in_sizes, int n_in,
                              void* d_out, int out_size, void* d_ws, size_t ws_size,
                              hipStream_t stream) {
    const float* x   = (const float*)d_in[0];
    const int*   ei  = (const int*)d_in[1];
    const float* W1  = (const float*)d_in[2];
    const float* b1  = (const float*)d_in[3];
    const float* Wmu = (const float*)d_in[4];
    const float* bmu = (const float*)d_in[5];
    const float* Wls = (const float*)d_in[6];
    const float* bls = (const float*)d_in[7];
    const float* eps = (const float*)d_in[8];

    const int n = in_sizes[0] / 256;   // 100000
    const int E = in_sizes[1] / 2;     // 1600000
    const int* srcv = ei;
    const int* dstv = ei + E;
    const int nbuck = (n + 511) >> BSHIFT;

    char* w = (char*)d_ws;
    auto alloc = [&](size_t bytes) -> char* {
        char* p = w;
        w += (bytes + 255) & ~(size_t)255;
        return p;
    };
    float* dinv     = (float*)alloc((size_t)n * 4);
    int*   rowstart = (int*)alloc((size_t)(n + 1) * 4);
    int*   gcnt     = (int*)alloc((size_t)NBUCK_MAX * 4);
    int*   bstart   = (int*)alloc((size_t)(NBUCK_MAX + 1) * 4);
    int*   bcur     = (int*)alloc((size_t)NBUCK_MAX * 4);
    int*   colv     = (int*)alloc((size_t)E * 4);
    unsigned long long* ebuf = (unsigned long long*)alloc((size_t)E * 8);
    unsigned short* B1h = (unsigned short*)alloc(128 * 256 * 2);
    unsigned short* B1l = (unsigned short*)alloc(128 * 256 * 2);
    unsigned short* B2h = (unsigned short*)alloc(128 * 128 * 2);
    unsigned short* B2l = (unsigned short*)alloc(128 * 128 * 2);
    unsigned short* hbuf = (unsigned short*)alloc((size_t)n * 128 * 2);  // h', then agg
    unsigned short* hid  = (unsigned short*)alloc((size_t)n * 128 * 2);  // hidden'

    const int ecb = (E + 4095) / 4096;

    hipMemsetAsync(gcnt, 0, NBUCK_MAX * 4, stream);
    k_hist<<<ecb, 256, 0, stream>>>(dstv, gcnt, E);
    k_scanb<<<1, 256, 0, stream>>>(gcnt, bstart, bcur, nbuck, E);
    k_scatb<<<ecb, 256, 0, stream>>>(srcv, dstv, bcur, ebuf, E);
    k_bsort<<<nbuck, 512, 0, stream>>>(ebuf, bstart, colv, rowstart, dinv, n, nbuck, E);
    k_prepB<<<128, 256, 0, stream>>>(W1, Wmu, Wls, B1h, B1l, B2h, B2l);

    k_gemm1<<<(n + 63) / 64, 256, 0, stream>>>(x, B1h, B1l, dinv, hbuf, n);
    k_prop1<<<(n + 3) / 4, 256, 0, stream>>>(hbuf, colv, rowstart, dinv, b1, hid, n);
    k_prop2<<<(n + 3) / 4, 256, 0, stream>>>(hid, colv, rowstart, dinv, hbuf, n);

    float* zout  = (float*)d_out;
    float* muout = zout + (size_t)n * 64;
    float* lsout = muout + (size_t)n * 64;
    k_gemm2z<<<(n + 63) / 64, 256, 0, stream>>>(hbuf, B2h, B2l, bmu, bls, eps,
                                                zout, muout, lsout, n);
}

// Round 6
// 275.162 us; speedup vs baseline: 1.4780x; 1.4780x over previous
//
#include <hip/hip_runtime.h>
#include <cstdint>
#include <cstddef>

typedef __attribute__((ext_vector_type(8))) short short8v;   // 8 bf16 / 4 VGPRs
typedef __attribute__((ext_vector_type(4))) float f32x4;

#define BSHIFT 9            // 512 nodes per bucket
#define NBUCK_MAX 256

__device__ __forceinline__ unsigned short f2bf_rne(float x) {
    unsigned int u = __float_as_uint(x);
    return (unsigned short)((u + 0x7fffu + ((u >> 16) & 1u)) >> 16);
}
__device__ __forceinline__ float bf2f(unsigned short h) {
    return __uint_as_float(((unsigned int)h) << 16);
}
__device__ __forceinline__ float bflo(unsigned int u) { return __uint_as_float(u << 16); }
__device__ __forceinline__ float bfhi(unsigned int u) { return __uint_as_float(u & 0xffff0000u); }

__device__ __forceinline__ void acc8(float* a, uint4 v) {
    a[0] += bflo(v.x); a[1] += bfhi(v.x);
    a[2] += bflo(v.y); a[3] += bfhi(v.y);
    a[4] += bflo(v.z); a[5] += bfhi(v.z);
    a[6] += bflo(v.w); a[7] += bfhi(v.w);
}

// ---------------- CSR build: bucketed (512 nodes/bucket) ----------------

__global__ __launch_bounds__(256) void k_hist(const int* __restrict__ dstv,
                                              int* __restrict__ gcnt, int E) {
    __shared__ int h[NBUCK_MAX];
    int t = threadIdx.x;
    for (int b = t; b < NBUCK_MAX; b += 256) h[b] = 0;
    __syncthreads();
    int base = blockIdx.x * 4096;
    for (int q = 0; q < 16; ++q) {
        int i = base + q * 256 + t;
        if (i < E) atomicAdd(&h[dstv[i] >> BSHIFT], 1);
    }
    __syncthreads();
    for (int b = t; b < NBUCK_MAX; b += 256)
        if (h[b]) atomicAdd(&gcnt[b], h[b]);
}

__global__ __launch_bounds__(256) void k_scanb(const int* __restrict__ gcnt,
                                               int* __restrict__ bstart,
                                               int* __restrict__ bcur, int nbuck, int E) {
    __shared__ int s[256];
    int t = threadIdx.x;
    int v = (t < nbuck) ? gcnt[t] : 0;
    s[t] = v;
    __syncthreads();
    for (int off = 1; off < 256; off <<= 1) {
        int x = 0;
        if (t >= off) x = s[t - off];
        __syncthreads();
        if (t >= off) s[t] += x;
        __syncthreads();
    }
    if (t < nbuck) { int ex = s[t] - v; bstart[t] = ex; bcur[t] = ex; }
    if (t == 0) bstart[nbuck] = E;
}

__global__ __launch_bounds__(256) void k_scatb(const int* __restrict__ srcv,
                                               const int* __restrict__ dstv,
                                               int* __restrict__ bcur,
                                               unsigned long long* __restrict__ ebuf, int E) {
    __shared__ int hcnt[NBUCK_MAX], hbase[NBUCK_MAX], hcur[NBUCK_MAX];
    int t = threadIdx.x;
    for (int b = t; b < NBUCK_MAX; b += 256) { hcnt[b] = 0; hcur[b] = 0; }
    __syncthreads();
    int base = blockIdx.x * 4096;
    for (int q = 0; q < 16; ++q) {
        int i = base + q * 256 + t;
        if (i < E) atomicAdd(&hcnt[dstv[i] >> BSHIFT], 1);
    }
    __syncthreads();
    for (int b = t; b < NBUCK_MAX; b += 256)
        hbase[b] = hcnt[b] ? atomicAdd(&bcur[b], hcnt[b]) : 0;
    __syncthreads();
    for (int q = 0; q < 16; ++q) {
        int i = base + q * 256 + t;
        if (i < E) {
            int d = dstv[i], b = d >> BSHIFT;
            int off = atomicAdd(&hcur[b], 1);
            ebuf[hbase[b] + off] =
                (unsigned long long)(unsigned)srcv[i] | ((unsigned long long)(unsigned)d << 32);
        }
    }
}

__global__ __launch_bounds__(512) void k_bsort(const unsigned long long* __restrict__ ebuf,
                                               const int* __restrict__ bstart,
                                               int* __restrict__ colv,
                                               int* __restrict__ rowstart,
                                               float* __restrict__ dinv,
                                               int n, int nbuck, int E) {
    __shared__ int cnt[512], sc[512], cur[512];
    int t = threadIdx.x;
    int b = blockIdx.x;
    int node0 = b << BSHIFT;
    int nn = min(512, n - node0);
    cnt[t] = 0;
    __syncthreads();
    int s0 = bstart[b], e0 = bstart[b + 1];
    for (int i = s0 + t; i < e0; i += 512) {
        int d = (int)(ebuf[i] >> 32);
        atomicAdd(&cnt[d - node0], 1);
    }
    __syncthreads();
    int v = cnt[t];
    sc[t] = v;
    __syncthreads();
    for (int off = 1; off < 512; off <<= 1) {
        int x = 0;
        if (t >= off) x = sc[t - off];
        __syncthreads();
        if (t >= off) sc[t] += x;
        __syncthreads();
    }
    if (t < nn) {
        int rs = s0 + sc[t] - v;
        cur[t] = rs;
        rowstart[node0 + t] = rs;
        dinv[node0 + t] = rsqrtf((float)(v + 1));   // +1 self-loop
    }
    if (b == nbuck - 1 && t == 0) rowstart[n] = E;
    __syncthreads();
    for (int i = s0 + t; i < e0; i += 512) {
        unsigned long long pv = ebuf[i];
        int d = (int)(pv >> 32);
        int pos = atomicAdd(&cur[d - node0], 1);
        colv[pos] = (int)(unsigned)(pv & 0xffffffffu);
    }
}

// ---------------- weight prep: f32 -> bf16 (hi only), transposed [mfma_col][K] ----------------
// MFMA col c -> output channel ch(c) = (c&15)*8 + (c>>4): lane lr owns channels lr*8..lr*8+7.

__global__ __launch_bounds__(256) void k_prepB(const float* __restrict__ W1,
                                               const float* __restrict__ Wmu,
                                               const float* __restrict__ Wls,
                                               unsigned short* __restrict__ B1h,
                                               unsigned short* __restrict__ B2h) {
    int i = blockIdx.x * 256 + threadIdx.x;
    if (i < 256 * 128) {               // W1 [256][128]
        int k = i >> 7, c = i & 127;
        int ch = ((c & 15) << 3) | (c >> 4);
        B1h[c * 256 + k] = f2bf_rne(W1[k * 128 + ch]);
    }
    if (i < 128 * 128) {               // [Wmu|Wls] [128][128]
        int k = i >> 7, c = i & 127;
        int ch = ((c & 15) << 3) | (c >> 4);
        float vv = (ch < 64) ? Wmu[k * 64 + ch] : Wls[k * 64 + (ch - 64)];
        B2h[c * 128 + k] = f2bf_rne(vv);
    }
}

// ---------------- GEMM1: h' = dinv .* (x @ W1), out bf16 [n][128] ----------------
// Block = 4 waves x 32 rows = 128 rows. Whole B-hi (64KB) staged in LDS once;
// barrier-free K-loop: ds_read B frags + streaming A + MFMA (A split hi/lo: 2 MFMA).

__global__ __launch_bounds__(256) void k_gemm1(const float* __restrict__ A,
                                               const unsigned short* __restrict__ Bth,
                                               const float* __restrict__ dinv,
                                               unsigned short* __restrict__ Cb, int M) {
    const int K = 256;
    __shared__ unsigned short Bs[128 * 256];   // 64 KB
    const int tid = threadIdx.x;
    const int w = tid >> 6, l = tid & 63;
    const int lr = l & 15, lq = l >> 4;
    const int row0 = blockIdx.x * 128 + w * 32;

    // stage B-hi: chunk rw = s*8+ct ; lane l holds 16B at Bt[(ct*16+lr)*K + s*32 + lq*8]
#pragma unroll
    for (int r = 0; r < 16; ++r) {
        int rw = r * 4 + w;
        int s = rw >> 3, ct = rw & 7;
        short8v v = *(const short8v*)(Bth + (size_t)(ct * 16 + lr) * K + s * 32 + lq * 8);
        *(short8v*)(&Bs[(rw * 64 + l) * 8]) = v;
    }
    __syncthreads();

    f32x4 acc[2][8];
#pragma unroll
    for (int rt = 0; rt < 2; ++rt)
#pragma unroll
        for (int ct = 0; ct < 8; ++ct) acc[rt][ct] = (f32x4){0.f, 0.f, 0.f, 0.f};

    int r0g = row0 + lr, r1g = row0 + 16 + lr;
    const float* a0p = A + (size_t)(r0g < M ? r0g : 0) * K + lq * 8;
    const float* a1p = A + (size_t)(r1g < M ? r1g : 0) * K + lq * 8;

#pragma unroll
    for (int s = 0; s < 8; ++s) {
        float4 fa0 = *(const float4*)(a0p + s * 32);
        float4 fb0 = *(const float4*)(a0p + s * 32 + 4);
        float4 fa1 = *(const float4*)(a1p + s * 32);
        float4 fb1 = *(const float4*)(a1p + s * 32 + 4);
        float av0[8] = {fa0.x, fa0.y, fa0.z, fa0.w, fb0.x, fb0.y, fb0.z, fb0.w};
        float av1[8] = {fa1.x, fa1.y, fa1.z, fa1.w, fb1.x, fb1.y, fb1.z, fb1.w};
        short8v ah0, al0, ah1, al1;
#pragma unroll
        for (int q = 0; q < 8; ++q) {
            unsigned short h0 = f2bf_rne(av0[q]);
            ah0[q] = (short)h0;
            al0[q] = (short)f2bf_rne(av0[q] - bf2f(h0));
            unsigned short h1 = f2bf_rne(av1[q]);
            ah1[q] = (short)h1;
            al1[q] = (short)f2bf_rne(av1[q] - bf2f(h1));
        }
#pragma unroll
        for (int ct = 0; ct < 8; ++ct) {
            short8v bh = *(const short8v*)(&Bs[((s * 8 + ct) * 64 + l) * 8]);
            acc[0][ct] = __builtin_amdgcn_mfma_f32_16x16x32_bf16(ah0, bh, acc[0][ct], 0, 0, 0);
            acc[0][ct] = __builtin_amdgcn_mfma_f32_16x16x32_bf16(al0, bh, acc[0][ct], 0, 0, 0);
            acc[1][ct] = __builtin_amdgcn_mfma_f32_16x16x32_bf16(ah1, bh, acc[1][ct], 0, 0, 0);
            acc[1][ct] = __builtin_amdgcn_mfma_f32_16x16x32_bf16(al1, bh, acc[1][ct], 0, 0, 0);
        }
    }

    // D: col(lr) -> channels lr*8+ct ; row = rt*16 + (l>>4)*4 + j
#pragma unroll
    for (int rt = 0; rt < 2; ++rt) {
        int rbase = row0 + rt * 16 + (lq << 2);
#pragma unroll
        for (int j = 0; j < 4; ++j) {
            int row = rbase + j;
            if (row < M) {
                float dv = dinv[row];
                short8v r;
#pragma unroll
                for (int ct = 0; ct < 8; ++ct) r[ct] = (short)f2bf_rne(dv * acc[rt][ct][j]);
                *(short8v*)(Cb + (size_t)row * 128 + lr * 8) = r;
            }
        }
    }
}

// ---------------- prop1: hidden' = dinv .* relu(dinv_v * (sum h'_c + h'_v) + b1), bf16 ----------------
// 4 nodes per wave: 16 lanes x 16B own a full row slice; edges serial, unroll 4.

__global__ __launch_bounds__(256) void k_prop1(const unsigned short* __restrict__ hb,
                                               const int* __restrict__ colv,
                                               const int* __restrict__ rowstart,
                                               const float* __restrict__ dinv,
                                               const float* __restrict__ bias,
                                               unsigned short* __restrict__ ob, int n) {
    int wid = (blockIdx.x * 256 + threadIdx.x) >> 6;
    int nid = wid * 4 + ((threadIdx.x >> 4) & 3);
    if (nid >= n) return;
    int cl = threadIdx.x & 15;
    int s = rowstart[nid], e = rowstart[nid + 1];
    float a[8] = {0.f, 0.f, 0.f, 0.f, 0.f, 0.f, 0.f, 0.f};
    int i = s;
    for (; i + 4 <= e; i += 4) {
        int c0 = colv[i], c1 = colv[i + 1], c2 = colv[i + 2], c3 = colv[i + 3];
        uint4 v0 = *(const uint4*)(hb + (size_t)c0 * 128 + cl * 8);
        uint4 v1 = *(const uint4*)(hb + (size_t)c1 * 128 + cl * 8);
        uint4 v2 = *(const uint4*)(hb + (size_t)c2 * 128 + cl * 8);
        uint4 v3 = *(const uint4*)(hb + (size_t)c3 * 128 + cl * 8);
        acc8(a, v0); acc8(a, v1); acc8(a, v2); acc8(a, v3);
    }
    for (; i < e; ++i) {
        int c = colv[i];
        uint4 v = *(const uint4*)(hb + (size_t)c * 128 + cl * 8);
        acc8(a, v);
    }
    uint4 vo = *(const uint4*)(hb + (size_t)nid * 128 + cl * 8);   // self-loop
    acc8(a, vo);
    float dv = dinv[nid];
    float4 b0 = *(const float4*)(bias + cl * 8);
    float4 b1v = *(const float4*)(bias + cl * 8 + 4);
    float bb[8] = {b0.x, b0.y, b0.z, b0.w, b1v.x, b1v.y, b1v.z, b1v.w};
    short8v r;
#pragma unroll
    for (int k = 0; k < 8; ++k)
        r[k] = (short)f2bf_rne(fmaxf(a[k] * dv + bb[k], 0.f) * dv);   // fold next-layer dinv
    *(short8v*)(ob + (size_t)nid * 128 + cl * 8) = r;
}

// ---------------- prop2: agg = dinv_v * (sum hidden'_c + hidden'_v), bf16 ----------------

__global__ __launch_bounds__(256) void k_prop2(const unsigned short* __restrict__ hb,
                                               const int* __restrict__ colv,
                                               const int* __restrict__ rowstart,
                                               const float* __restrict__ dinv,
                                               unsigned short* __restrict__ ob, int n) {
    int wid = (blockIdx.x * 256 + threadIdx.x) >> 6;
    int nid = wid * 4 + ((threadIdx.x >> 4) & 3);
    if (nid >= n) return;
    int cl = threadIdx.x & 15;
    int s = rowstart[nid], e = rowstart[nid + 1];
    float a[8] = {0.f, 0.f, 0.f, 0.f, 0.f, 0.f, 0.f, 0.f};
    int i = s;
    for (; i + 4 <= e; i += 4) {
        int c0 = colv[i], c1 = colv[i + 1], c2 = colv[i + 2], c3 = colv[i + 3];
        uint4 v0 = *(const uint4*)(hb + (size_t)c0 * 128 + cl * 8);
        uint4 v1 = *(const uint4*)(hb + (size_t)c1 * 128 + cl * 8);
        uint4 v2 = *(const uint4*)(hb + (size_t)c2 * 128 + cl * 8);
        uint4 v3 = *(const uint4*)(hb + (size_t)c3 * 128 + cl * 8);
        acc8(a, v0); acc8(a, v1); acc8(a, v2); acc8(a, v3);
    }
    for (; i < e; ++i) {
        int c = colv[i];
        uint4 v = *(const uint4*)(hb + (size_t)c * 128 + cl * 8);
        acc8(a, v);
    }
    uint4 vo = *(const uint4*)(hb + (size_t)nid * 128 + cl * 8);
    acc8(a, vo);
    float dv = dinv[nid];
    short8v r;
#pragma unroll
    for (int k = 0; k < 8; ++k) r[k] = (short)f2bf_rne(a[k] * dv);
    *(short8v*)(ob + (size_t)nid * 128 + cl * 8) = r;
}

// ---------------- GEMM2 + epilogue: [mu|ls] = agg @ [Wmu|Wls] + b ; z = mu + eps*exp(ls) ----------------
// Block = 4 waves x 32 rows; B2-hi (32KB) in LDS; A bf16 exact (1 MFMA per ct).

__global__ __launch_bounds__(256) void k_gemm2z(const unsigned short* __restrict__ Ab,
                                                const unsigned short* __restrict__ Bth,
                                                const float* __restrict__ bmu,
                                                const float* __restrict__ bls,
                                                const float* __restrict__ eps,
                                                float* __restrict__ zout,
                                                float* __restrict__ muout,
                                                float* __restrict__ lsout, int M) {
    const int K = 128;
    __shared__ unsigned short Bs[128 * 128];   // 32 KB
    const int tid = threadIdx.x;
    const int w = tid >> 6, l = tid & 63;
    const int lr = l & 15, lq = l >> 4;
    const int row0 = blockIdx.x * 128 + w * 32;

#pragma unroll
    for (int r = 0; r < 8; ++r) {
        int rw = r * 4 + w;
        int s = rw >> 3, ct = rw & 7;
        short8v v = *(const short8v*)(Bth + (size_t)(ct * 16 + lr) * K + s * 32 + lq * 8);
        *(short8v*)(&Bs[(rw * 64 + l) * 8]) = v;
    }
    __syncthreads();

    f32x4 acc[2][8];
#pragma unroll
    for (int rt = 0; rt < 2; ++rt)
#pragma unroll
        for (int ct = 0; ct < 8; ++ct) acc[rt][ct] = (f32x4){0.f, 0.f, 0.f, 0.f};

    int r0g = row0 + lr, r1g = row0 + 16 + lr;
    const unsigned short* a0p = Ab + (size_t)(r0g < M ? r0g : 0) * K + lq * 8;
    const unsigned short* a1p = Ab + (size_t)(r1g < M ? r1g : 0) * K + lq * 8;

#pragma unroll
    for (int s = 0; s < 4; ++s) {
        short8v a0 = *(const short8v*)(a0p + s * 32);
        short8v a1 = *(const short8v*)(a1p + s * 32);
#pragma unroll
        for (int ct = 0; ct < 8; ++ct) {
            short8v bh = *(const short8v*)(&Bs[((s * 8 + ct) * 64 + l) * 8]);
            acc[0][ct] = __builtin_amdgcn_mfma_f32_16x16x32_bf16(a0, bh, acc[0][ct], 0, 0, 0);
            acc[1][ct] = __builtin_amdgcn_mfma_f32_16x16x32_bf16(a1, bh, acc[1][ct], 0, 0, 0);
        }
    }

    const bool isMu = (lr < 8);
    float bb[8];
#pragma unroll
    for (int ct = 0; ct < 8; ++ct)
        bb[ct] = isMu ? bmu[lr * 8 + ct] : bls[(lr - 8) * 8 + ct];

#pragma unroll
    for (int rt = 0; rt < 2; ++rt) {
        int rbase = row0 + rt * 16 + (lq << 2);
#pragma unroll
        for (int j = 0; j < 4; ++j) {
            int row = rbase + j;
            float val[8], ex[8], exs[8];
#pragma unroll
            for (int ct = 0; ct < 8; ++ct) {
                val[ct] = acc[rt][ct][j] + bb[ct];
                ex[ct] = __expf(val[ct]);
            }
#pragma unroll
            for (int ct = 0; ct < 8; ++ct) exs[ct] = __shfl(ex[ct], l + 8);  // ls partner
            if (row < M) {
                if (isMu) {
                    size_t o = (size_t)row * 64 + lr * 8;
                    float4 e0 = *(const float4*)(eps + o);
                    float4 e1 = *(const float4*)(eps + o + 4);
                    float epv[8] = {e0.x, e0.y, e0.z, e0.w, e1.x, e1.y, e1.z, e1.w};
                    float z[8];
#pragma unroll
                    for (int ct = 0; ct < 8; ++ct) z[ct] = val[ct] + epv[ct] * exs[ct];
                    *(float4*)(zout + o)     = make_float4(z[0], z[1], z[2], z[3]);
                    *(float4*)(zout + o + 4) = make_float4(z[4], z[5], z[6], z[7]);
                    *(float4*)(muout + o)     = make_float4(val[0], val[1], val[2], val[3]);
                    *(float4*)(muout + o + 4) = make_float4(val[4], val[5], val[6], val[7]);
                } else {
                    size_t o = (size_t)row * 64 + (lr - 8) * 8;
                    *(float4*)(lsout + o)     = make_float4(val[0], val[1], val[2], val[3]);
                    *(float4*)(lsout + o + 4) = make_float4(val[4], val[5], val[6], val[7]);
                }
            }
        }
    }
}

// ---------------- launch ----------------

extern "C" void kernel_launch(void* const* d_in, const int* in_sizes, int n_in,
                              void* d_out, int out_size, void* d_ws, size_t ws_size,
                              hipStream_t stream) {
    const float* x   = (const float*)d_in[0];
    const int*   ei  = (const int*)d_in[1];
    const float* W1  = (const float*)d_in[2];
    const float* b1  = (const float*)d_in[3];
    const float* Wmu = (const float*)d_in[4];
    const float* bmu = (const float*)d_in[5];
    const float* Wls = (const float*)d_in[6];
    const float* bls = (const float*)d_in[7];
    const float* eps = (const float*)d_in[8];

    const int n = in_sizes[0] / 256;   // 100000
    const int E = in_sizes[1] / 2;     // 1600000
    const int* srcv = ei;
    const int* dstv = ei + E;
    const int nbuck = (n + 511) >> BSHIFT;

    char* w = (char*)d_ws;
    auto alloc = [&](size_t bytes) -> char* {
        char* p = w;
        w += (bytes + 255) & ~(size_t)255;
        return p;
    };
    float* dinv     = (float*)alloc((size_t)n * 4);
    int*   rowstart = (int*)alloc((size_t)(n + 1) * 4);
    int*   gcnt     = (int*)alloc((size_t)NBUCK_MAX * 4);
    int*   bstart   = (int*)alloc((size_t)(NBUCK_MAX + 1) * 4);
    int*   bcur     = (int*)alloc((size_t)NBUCK_MAX * 4);
    int*   colv     = (int*)alloc((size_t)E * 4);
    unsigned long long* ebuf = (unsigned long long*)alloc((size_t)E * 8);
    unsigned short* B1h = (unsigned short*)alloc(128 * 256 * 2);
    unsigned short* B2h = (unsigned short*)alloc(128 * 128 * 2);
    unsigned short* hbuf = (unsigned short*)alloc((size_t)n * 128 * 2);  // h', then agg
    unsigned short* hid  = (unsigned short*)alloc((size_t)n * 128 * 2);  // hidden'

    const int ecb = (E + 4095) / 4096;

    hipMemsetAsync(gcnt, 0, NBUCK_MAX * 4, stream);
    k_hist<<<ecb, 256, 0, stream>>>(dstv, gcnt, E);
    k_scanb<<<1, 256, 0, stream>>>(gcnt, bstart, bcur, nbuck, E);
    k_scatb<<<ecb, 256, 0, stream>>>(srcv, dstv, bcur, ebuf, E);
    k_bsort<<<nbuck, 512, 0, stream>>>(ebuf, bstart, colv, rowstart, dinv, n, nbuck, E);
    k_prepB<<<128, 256, 0, stream>>>(W1, Wmu, Wls, B1h, B2h);

    k_gemm1<<<(n + 127) / 128, 256, 0, stream>>>(x, B1h, dinv, hbuf, n);
    k_prop1<<<(n + 15) / 16, 256, 0, stream>>>(hbuf, colv, rowstart, dinv, b1, hid, n);
    k_prop2<<<(n + 15) / 16, 256, 0, stream>>>(hid, colv, rowstart, dinv, hbuf, n);

    float* zout  = (float*)d_out;
    float* muout = zout + (size_t)n * 64;
    float* lsout = muout + (size_t)n * 64;
    k_gemm2z<<<(n + 127) / 128, 256, 0, stream>>>(hbuf, B2h, bmu, bls, eps,
                                                  zout, muout, lsout, n);
}